// Round 2
// baseline (371.972 us; speedup 1.0000x reference)
//
#include <hip/hip_runtime.h>

// MultiheadAttentionWithBias: B=2, L=2048, D=1024, H=16, HD=64
// Pipeline: cvt(f32->bf16) -> QKV GEMM (bf16 MFMA) -> V transpose ->
//           flash attention w/ f32 bias (depth-2 bias prefetch) -> out GEMM.

typedef __attribute__((ext_vector_type(8))) short bf16x8;
typedef __attribute__((ext_vector_type(4))) float f32x4;
typedef __attribute__((ext_vector_type(8))) unsigned short u16x8;
using u16 = unsigned short;

#define MFMA16(a, b, c) __builtin_amdgcn_mfma_f32_16x16x32_bf16((a), (b), (c), 0, 0, 0)
#define LOG2E 1.44269504088896f
#define QSCALE (0.125f * 1.44269504088896f)

__device__ __forceinline__ u16 f2bf(float f) {
  union { float f; unsigned int u; } v; v.f = f;
  unsigned int r = v.u + 0x7FFFu + ((v.u >> 16) & 1u);
  return (u16)(r >> 16);
}

__device__ __forceinline__ void g2lds16(const void* gsrc, void* ldst) {
  __builtin_amdgcn_global_load_lds(
      (const __attribute__((address_space(1))) unsigned int*)gsrc,
      (__attribute__((address_space(3))) unsigned int*)ldst, 16, 0, 0);
}

// ---------------- f32 -> bf16 convert, 8 elems/thread ----------------
__global__ __launch_bounds__(256) void cvt_kernel(const float* __restrict__ src,
                                                  u16* __restrict__ dst, int n8) {
  int i = blockIdx.x * 256 + threadIdx.x;
  if (i >= n8) return;
  const float4* s = (const float4*)src;
  float4 a = s[2 * i], b = s[2 * i + 1];
  u16x8 o;
  o[0] = f2bf(a.x); o[1] = f2bf(a.y); o[2] = f2bf(a.z); o[3] = f2bf(a.w);
  o[4] = f2bf(b.x); o[5] = f2bf(b.y); o[6] = f2bf(b.z); o[7] = f2bf(b.w);
  ((u16x8*)dst)[i] = o;
}

// ---------------- GEMM C = A * B^T ----------------
template <int MODE>
__global__ __launch_bounds__(256, 2) void gemm_bt(
    const u16* __restrict__ A, const u16* __restrict__ B,
    u16* __restrict__ qp, u16* __restrict__ kp, u16* __restrict__ vp,
    const float* __restrict__ b0, const float* __restrict__ b1,
    const float* __restrict__ b2, float* __restrict__ outp,
    const float* __restrict__ bo) {
  __shared__ __align__(16) u16 lA[128 * 64];
  __shared__ __align__(16) u16 lB[128 * 64];
  const int tid = threadIdx.x;
  const int lane = tid & 63, wid = tid >> 6;
  const int g = lane >> 4, cc = lane & 15;
  const int wr = wid >> 1, wc = wid & 1;
  const int m0 = blockIdx.y * 128, n0 = blockIdx.x * 128;
  f32x4 acc[4][4] = {};
  for (int kt = 0; kt < 16; ++kt) {
    const int kof = kt * 64;
#pragma unroll
    for (int i = 0; i < 4; ++i) {
      int cid = i * 256 + tid;
      int row = cid >> 3;
      int col = (cid & 7) * 8;
      g2lds16(A + (size_t)(m0 + row) * 1024 + kof + col, &lA[(i * 256 + wid * 64) * 8]);
      g2lds16(B + (size_t)(n0 + row) * 1024 + kof + col, &lB[(i * 256 + wid * 64) * 8]);
    }
    __syncthreads();
#pragma unroll
    for (int kc = 0; kc < 2; ++kc) {
      bf16x8 af[4], bfr[4];
#pragma unroll
      for (int mf = 0; mf < 4; ++mf)
        af[mf] = *(const bf16x8*)&lA[(wr * 64 + mf * 16 + cc) * 64 + kc * 32 + g * 8];
#pragma unroll
      for (int nf = 0; nf < 4; ++nf)
        bfr[nf] = *(const bf16x8*)&lB[(wc * 64 + nf * 16 + cc) * 64 + kc * 32 + g * 8];
#pragma unroll
      for (int mf = 0; mf < 4; ++mf)
#pragma unroll
        for (int nf = 0; nf < 4; ++nf)
          acc[mf][nf] = MFMA16(af[mf], bfr[nf], acc[mf][nf]);
    }
    __syncthreads();
  }
#pragma unroll
  for (int mf = 0; mf < 4; ++mf) {
#pragma unroll
    for (int nf = 0; nf < 4; ++nf) {
      int n = n0 + wc * 64 + nf * 16 + cc;
      if (MODE == 0) {
        int which = n >> 10;
        int nn = n & 1023;
        const float* bp = which == 0 ? b0 : (which == 1 ? b1 : b2);
        u16* dp = which == 0 ? qp : (which == 1 ? kp : vp);
        float bias = bp[nn];
        int h = nn >> 6, hd = nn & 63;
#pragma unroll
        for (int r = 0; r < 4; ++r) {
          int m = m0 + wr * 64 + mf * 16 + g * 4 + r;
          int bb = m >> 11, ll = m & 2047;
          float val = acc[mf][nf][r] + bias;
          if (which == 0) val *= QSCALE;
          dp[(((size_t)(bb * 16 + h)) * 2048 + ll) * 64 + hd] = f2bf(val);
        }
      } else {
        float bias = bo[n];
#pragma unroll
        for (int r = 0; r < 4; ++r) {
          int m = m0 + wr * 64 + mf * 16 + g * 4 + r;
          outp[(size_t)m * 1024 + n] = acc[mf][nf][r] + bias;
        }
      }
    }
  }
}

// ---------------- V transpose: [BH, L, 64] -> [BH, 64, L] ----------------
__global__ __launch_bounds__(256) void transpose_v(const u16* __restrict__ v,
                                                   u16* __restrict__ vt) {
  __shared__ u16 t[64 * 65];
  const int bh = blockIdx.y, l0 = blockIdx.x * 64;
  const int tid = threadIdx.x;
  const u16* src = v + ((size_t)bh * 2048 + l0) * 64;
#pragma unroll
  for (int it = 0; it < 2; ++it) {
    int idx = it * 256 + tid;
    int r = idx >> 3, c8 = (idx & 7) * 8;
    u16x8 val = *(const u16x8*)&src[r * 64 + c8];
#pragma unroll
    for (int j = 0; j < 8; ++j) t[r * 65 + c8 + j] = val[j];
  }
  __syncthreads();
  u16* dst = vt + (size_t)bh * 64 * 2048 + l0;
#pragma unroll
  for (int it = 0; it < 2; ++it) {
    int d = (tid >> 3) + it * 32;
    int ls = (tid & 7) * 8;
    u16x8 o;
#pragma unroll
    for (int j = 0; j < 8; ++j) o[j] = t[(ls + j) * 65 + d];
    *(u16x8*)&dst[(size_t)d * 2048 + ls] = o;
  }
}

// ---------------- Flash attention ----------------
// 4 waves/block: wave = (batch, q-strip). 16 q-rows per wave, 32 k-tiles of 64.
// Bias tile (the 256MB HBM stream) is register-prefetched DEPTH-2:
// at iter t we consume bias(t) and immediately refill the same regs with
// bias(t+2); tile t+1 is already in flight. K/V are L2/L3-resident (16MB) —
// loaded same-iter, V hoisted above the softmax chain so PV's vmcnt wait
// never drains the bias prefetch (issue order: V, K, then bias refill).
__global__ __launch_bounds__(256, 4) void attn_kernel(
    const u16* __restrict__ qm, const u16* __restrict__ km,
    const u16* __restrict__ vtm, const float* __restrict__ bias,
    u16* __restrict__ aout) {
  __shared__ __align__(16) u16 plds[4 * 16 * 64];  // per-wave 16x64 bf16 P tile
  const int tid = threadIdx.x;
  const int lane = tid & 63, wid = tid >> 6;
  const int g = lane >> 4, cc = lane & 15;
  const int b = wid >> 1, strip = wid & 1;
  const int h = blockIdx.y;
  const int q0 = blockIdx.x * 32 + strip * 16;
  const size_t bh = (size_t)b * 16 + h;
  const u16* qbase = qm + (bh * 2048 + q0) * 64;
  const u16* kbase = km + bh * 2048 * 64;
  const u16* vtbase = vtm + bh * 64 * 2048;
  // per-lane bias base: row (q0 + g*4), col cc
  const float* bbase = bias + ((size_t)h * 2048 + q0 + g * 4) * 2048 + cc;
  u16* pl = &plds[wid * 1024];

  bf16x8 qf0 = *(const bf16x8*)&qbase[(size_t)cc * 64 + g * 8];
  bf16x8 qf1 = *(const bf16x8*)&qbase[(size_t)cc * 64 + 32 + g * 8];
  f32x4 o[4] = {};
  float mrow[4], lrow[4];
#pragma unroll
  for (int r = 0; r < 4; ++r) { mrow[r] = -3.0e38f; lrow[r] = 0.f; }

  // depth-2 bias prefetch: bA = tile 0, bB = tile 1
  float bA[16], bB[16];
#pragma unroll
  for (int kb = 0; kb < 4; ++kb)
#pragma unroll
    for (int r = 0; r < 4; ++r) {
      bA[kb * 4 + r] = bbase[(size_t)r * 2048 + kb * 16];
      bB[kb * 4 + r] = bbase[(size_t)r * 2048 + 64 + kb * 16];
    }

#define ATTN_STEP(BC, kt_)                                                     \
  {                                                                            \
    const int k0 = (kt_) * 64;                                                 \
    const int kpre = ((kt_) + 2 < 32 ? (kt_) + 2 : 31) * 64;                   \
    /* V fragments first (oldest in vmcnt queue -> PV wait keeps bias live) */ \
    bf16x8 vf[8];                                                              \
    _Pragma("unroll") for (int td = 0; td < 4; ++td) {                         \
      const u16* vr = &vtbase[(size_t)(td * 16 + cc) * 2048 + k0 + g * 8];     \
      vf[td * 2] = *(const bf16x8*)vr;                                         \
      vf[td * 2 + 1] = *(const bf16x8*)(vr + 32);                              \
    }                                                                          \
    /* K fragments (L2/L3-resident) */                                         \
    bf16x8 kf[8];                                                              \
    _Pragma("unroll") for (int kb = 0; kb < 4; ++kb) {                         \
      const u16* kr = &kbase[(size_t)(k0 + kb * 16 + cc) * 64 + g * 8];        \
      kf[kb * 2] = *(const bf16x8*)kr;                                         \
      kf[kb * 2 + 1] = *(const bf16x8*)(kr + 32);                              \
    }                                                                          \
    f32x4 s[4];                                                                \
    _Pragma("unroll") for (int kb = 0; kb < 4; ++kb) {                         \
      f32x4 z = {};                                                            \
      z = MFMA16(qf0, kf[kb * 2], z);                                          \
      z = MFMA16(qf1, kf[kb * 2 + 1], z);                                      \
      s[kb] = z;                                                               \
    }                                                                          \
    /* consume prefetched bias, then refill same regs with tile kt+2 */       \
    _Pragma("unroll") for (int kb = 0; kb < 4; ++kb)                           \
        _Pragma("unroll") for (int r = 0; r < 4; ++r)                          \
            s[kb][r] += BC[kb * 4 + r] * LOG2E;                                \
    _Pragma("unroll") for (int kb = 0; kb < 4; ++kb)                           \
        _Pragma("unroll") for (int r = 0; r < 4; ++r)                          \
            BC[kb * 4 + r] = bbase[(size_t)r * 2048 + kpre + kb * 16];         \
    /* online softmax (rows live on 16 lanes, reduce over lane bits 0-3) */    \
    float rmax[4];                                                             \
    _Pragma("unroll") for (int r = 0; r < 4; ++r)                              \
        rmax[r] = fmaxf(fmaxf(s[0][r], s[1][r]), fmaxf(s[2][r], s[3][r]));     \
    _Pragma("unroll") for (int msk = 1; msk <= 8; msk <<= 1)                   \
        _Pragma("unroll") for (int r = 0; r < 4; ++r)                          \
            rmax[r] = fmaxf(rmax[r], __shfl_xor(rmax[r], msk, 64));            \
    float sc[4], ps[4];                                                        \
    _Pragma("unroll") for (int r = 0; r < 4; ++r) {                            \
      float mnew = fmaxf(mrow[r], rmax[r]);                                    \
      sc[r] = __builtin_amdgcn_exp2f(mrow[r] - mnew);                          \
      mrow[r] = mnew;                                                          \
    }                                                                          \
    _Pragma("unroll") for (int kb = 0; kb < 4; ++kb)                           \
        _Pragma("unroll") for (int r = 0; r < 4; ++r)                          \
            s[kb][r] = __builtin_amdgcn_exp2f(s[kb][r] - mrow[r]);             \
    _Pragma("unroll") for (int r = 0; r < 4; ++r)                              \
        ps[r] = (s[0][r] + s[1][r]) + (s[2][r] + s[3][r]);                     \
    _Pragma("unroll") for (int msk = 1; msk <= 8; msk <<= 1)                   \
        _Pragma("unroll") for (int r = 0; r < 4; ++r)                          \
            ps[r] += __shfl_xor(ps[r], msk, 64);                               \
    _Pragma("unroll") for (int r = 0; r < 4; ++r)                              \
        lrow[r] = lrow[r] * sc[r] + ps[r];                                     \
    _Pragma("unroll") for (int td = 0; td < 4; ++td)                           \
        _Pragma("unroll") for (int r = 0; r < 4; ++r) o[td][r] *= sc[r];       \
    /* P -> LDS (wave-private, XOR-swizzled 16B chunks) */                     \
    _Pragma("unroll") for (int kb = 0; kb < 4; ++kb)                           \
        _Pragma("unroll") for (int r = 0; r < 4; ++r) {                        \
      int row = g * 4 + r;                                                     \
      int pc = (kb * 2 + (cc >> 3)) ^ (row & 7);                               \
      pl[row * 64 + pc * 8 + (cc & 7)] = f2bf(s[kb][r]);                       \
    }                                                                          \
    bf16x8 pf0, pf1;                                                           \
    {                                                                          \
      int pc0 = (g) ^ (cc & 7);                                                \
      int pc1 = (4 + g) ^ (cc & 7);                                            \
      pf0 = *(const bf16x8*)&pl[cc * 64 + pc0 * 8];                            \
      pf1 = *(const bf16x8*)&pl[cc * 64 + pc1 * 8];                            \
    }                                                                          \
    _Pragma("unroll") for (int td = 0; td < 4; ++td) {                         \
      o[td] = MFMA16(pf0, vf[td * 2], o[td]);                                  \
      o[td] = MFMA16(pf1, vf[td * 2 + 1], o[td]);                              \
    }                                                                          \
  }

  for (int kt = 0; kt < 32; kt += 2) {
    ATTN_STEP(bA, kt);
    ATTN_STEP(bB, kt + 1);
  }
#undef ATTN_STEP

  // normalize + write attn output [B, L, 1024] bf16
#pragma unroll
  for (int td = 0; td < 4; ++td)
#pragma unroll
    for (int r = 0; r < 4; ++r) {
      float val = o[td][r] / lrow[r];
      int qg = q0 + g * 4 + r;
      aout[((size_t)b * 2048 + qg) * 1024 + h * 64 + td * 16 + cc] = f2bf(val);
    }
}

extern "C" void kernel_launch(void* const* d_in, const int* in_sizes, int n_in,
                              void* d_out, int out_size, void* d_ws, size_t ws_size,
                              hipStream_t stream) {
  const float* x  = (const float*)d_in[0];
  const float* rb = (const float*)d_in[1];
  const float* Wq = (const float*)d_in[2];
  const float* bq = (const float*)d_in[3];
  const float* Wk = (const float*)d_in[4];
  const float* bk = (const float*)d_in[5];
  const float* Wv = (const float*)d_in[6];
  const float* bv = (const float*)d_in[7];
  const float* Wo = (const float*)d_in[8];
  const float* bo = (const float*)d_in[9];
  float* out = (float*)d_out;
  char* ws = (char*)d_ws;

  u16* xb   = (u16*)(ws);                 // 8 MB  [4096,1024] bf16 (reused as aout)
  u16* W1b  = (u16*)(ws + (8 << 20));     // 6 MB  [3072,1024] bf16 (Wq|Wk|Wv)
  u16* Wob  = (u16*)(ws + (14 << 20));    // 2 MB  [1024,1024] bf16
  u16* qb   = (u16*)(ws + (16 << 20));    // 8 MB  [B,H,L,HD]
  u16* kb2  = (u16*)(ws + (24 << 20));    // 8 MB
  u16* vb   = (u16*)(ws + (32 << 20));    // 8 MB
  u16* vtb  = (u16*)(ws + (40 << 20));    // 8 MB  [B,H,HD,L]
  u16* aout = xb;                         // alias: xb dead after QKV GEMM

  cvt_kernel<<<2048, 256, 0, stream>>>(x, xb, 524288);
  cvt_kernel<<<512, 256, 0, stream>>>(Wq, W1b, 131072);
  cvt_kernel<<<512, 256, 0, stream>>>(Wk, W1b + (1 << 20), 131072);
  cvt_kernel<<<512, 256, 0, stream>>>(Wv, W1b + (2 << 20), 131072);
  cvt_kernel<<<512, 256, 0, stream>>>(Wo, Wob, 131072);

  gemm_bt<0><<<dim3(24, 32), 256, 0, stream>>>(xb, W1b, qb, kb2, vb, bq, bk, bv,
                                               nullptr, nullptr);
  transpose_v<<<dim3(32, 32), 256, 0, stream>>>(vb, vtb);
  attn_kernel<<<dim3(64, 16), 256, 0, stream>>>(qb, kb2, vtb, rb, aout);
  gemm_bt<1><<<dim3(8, 32), 256, 0, stream>>>(aout, Wob, nullptr, nullptr, nullptr,
                                              nullptr, nullptr, nullptr, out, bo);
}

// Round 3
// 223.839 us; speedup vs baseline: 1.6618x; 1.6618x over previous
//
#include <hip/hip_runtime.h>

// MultiheadAttentionWithBias: B=2, L=2048, D=1024, H=16, HD=64
// cvt(f32->bf16) -> QKV GEMM -> V transpose -> flash attn (LDS-staged K/V,
// swapped-QK^T S^T fragments, coalesced f32 bias, counted vmcnt) -> out GEMM.

typedef __attribute__((ext_vector_type(8))) short bf16x8;
typedef __attribute__((ext_vector_type(4))) float f32x4;
typedef __attribute__((ext_vector_type(8))) unsigned short u16x8;
using u16 = unsigned short;

#define MFMA16(a, b, c) __builtin_amdgcn_mfma_f32_16x16x32_bf16((a), (b), (c), 0, 0, 0)
#define LOG2E 1.44269504088896f
#define QSCALE (0.125f * 1.44269504088896f)

__device__ __forceinline__ u16 f2bf(float f) {
  union { float f; unsigned int u; } v; v.f = f;
  unsigned int r = v.u + 0x7FFFu + ((v.u >> 16) & 1u);
  return (u16)(r >> 16);
}

__device__ __forceinline__ unsigned cvt_pk_bf16(float lo, float hi) {
  unsigned r;
  asm volatile("v_cvt_pk_bf16_f32 %0, %1, %2" : "=v"(r) : "v"(lo), "v"(hi));
  return r;
}

__device__ __forceinline__ void g2lds16(const void* gsrc, void* ldst) {
  __builtin_amdgcn_global_load_lds(
      (const __attribute__((address_space(1))) unsigned int*)gsrc,
      (__attribute__((address_space(3))) unsigned int*)ldst, 16, 0, 0);
}

// ---------------- f32 -> bf16 convert ----------------
__global__ __launch_bounds__(256) void cvt_kernel(const float* __restrict__ src,
                                                  u16* __restrict__ dst, int n8) {
  int i = blockIdx.x * 256 + threadIdx.x;
  if (i >= n8) return;
  const float4* s = (const float4*)src;
  float4 a = s[2 * i], b = s[2 * i + 1];
  u16x8 o;
  o[0] = f2bf(a.x); o[1] = f2bf(a.y); o[2] = f2bf(a.z); o[3] = f2bf(a.w);
  o[4] = f2bf(b.x); o[5] = f2bf(b.y); o[6] = f2bf(b.z); o[7] = f2bf(b.w);
  ((u16x8*)dst)[i] = o;
}

// ---------------- GEMM C = A * B^T ----------------
template <int MODE>
__global__ __launch_bounds__(256, 2) void gemm_bt(
    const u16* __restrict__ A, const u16* __restrict__ B,
    u16* __restrict__ qp, u16* __restrict__ kp, u16* __restrict__ vp,
    const float* __restrict__ b0, const float* __restrict__ b1,
    const float* __restrict__ b2, float* __restrict__ outp,
    const float* __restrict__ bo) {
  __shared__ __align__(16) u16 lA[128 * 64];
  __shared__ __align__(16) u16 lB[128 * 64];
  const int tid = threadIdx.x;
  const int lane = tid & 63, wid = tid >> 6;
  const int g = lane >> 4, cc = lane & 15;
  const int wr = wid >> 1, wc = wid & 1;
  const int m0 = blockIdx.y * 128, n0 = blockIdx.x * 128;
  f32x4 acc[4][4] = {};
  for (int kt = 0; kt < 16; ++kt) {
    const int kof = kt * 64;
#pragma unroll
    for (int i = 0; i < 4; ++i) {
      int cid = i * 256 + tid;
      int row = cid >> 3;
      int col = (cid & 7) * 8;
      g2lds16(A + (size_t)(m0 + row) * 1024 + kof + col, &lA[(i * 256 + wid * 64) * 8]);
      g2lds16(B + (size_t)(n0 + row) * 1024 + kof + col, &lB[(i * 256 + wid * 64) * 8]);
    }
    __syncthreads();
#pragma unroll
    for (int kc = 0; kc < 2; ++kc) {
      bf16x8 af[4], bfr[4];
#pragma unroll
      for (int mf = 0; mf < 4; ++mf)
        af[mf] = *(const bf16x8*)&lA[(wr * 64 + mf * 16 + cc) * 64 + kc * 32 + g * 8];
#pragma unroll
      for (int nf = 0; nf < 4; ++nf)
        bfr[nf] = *(const bf16x8*)&lB[(wc * 64 + nf * 16 + cc) * 64 + kc * 32 + g * 8];
#pragma unroll
      for (int mf = 0; mf < 4; ++mf)
#pragma unroll
        for (int nf = 0; nf < 4; ++nf)
          acc[mf][nf] = MFMA16(af[mf], bfr[nf], acc[mf][nf]);
    }
    __syncthreads();
  }
#pragma unroll
  for (int mf = 0; mf < 4; ++mf) {
#pragma unroll
    for (int nf = 0; nf < 4; ++nf) {
      int n = n0 + wc * 64 + nf * 16 + cc;
      if (MODE == 0) {
        int which = n >> 10;
        int nn = n & 1023;
        const float* bp = which == 0 ? b0 : (which == 1 ? b1 : b2);
        u16* dp = which == 0 ? qp : (which == 1 ? kp : vp);
        float bias = bp[nn];
        int h = nn >> 6, hd = nn & 63;
#pragma unroll
        for (int r = 0; r < 4; ++r) {
          int m = m0 + wr * 64 + mf * 16 + g * 4 + r;
          int bb = m >> 11, ll = m & 2047;
          float val = acc[mf][nf][r] + bias;
          if (which == 0) val *= QSCALE;
          dp[(((size_t)(bb * 16 + h)) * 2048 + ll) * 64 + hd] = f2bf(val);
        }
      } else {
        float bias = bo[n];
#pragma unroll
        for (int r = 0; r < 4; ++r) {
          int m = m0 + wr * 64 + mf * 16 + g * 4 + r;
          outp[(size_t)m * 1024 + n] = acc[mf][nf][r] + bias;
        }
      }
    }
  }
}

// ---------------- V transpose: [BH, L, 64] -> [BH, 64, L] ----------------
__global__ __launch_bounds__(256) void transpose_v(const u16* __restrict__ v,
                                                   u16* __restrict__ vt) {
  __shared__ u16 t[64 * 65];
  const int bh = blockIdx.y, l0 = blockIdx.x * 64;
  const int tid = threadIdx.x;
  const u16* src = v + ((size_t)bh * 2048 + l0) * 64;
#pragma unroll
  for (int it = 0; it < 2; ++it) {
    int idx = it * 256 + tid;
    int r = idx >> 3, c8 = (idx & 7) * 8;
    u16x8 val = *(const u16x8*)&src[r * 64 + c8];
#pragma unroll
    for (int j = 0; j < 8; ++j) t[r * 65 + c8 + j] = val[j];
  }
  __syncthreads();
  u16* dst = vt + (size_t)bh * 64 * 2048 + l0;
#pragma unroll
  for (int it = 0; it < 2; ++it) {
    int d = (tid >> 3) + it * 32;
    int ls = (tid & 7) * 8;
    u16x8 o;
#pragma unroll
    for (int j = 0; j < 8; ++j) o[j] = t[(ls + j) * 65 + d];
    *(u16x8*)&dst[(size_t)d * 2048 + ls] = o;
  }
}

// ---------------- Flash attention (LDS-staged K/V, swapped QK^T) ----------------
// Block = 4 waves: wave = (batch b, strip). Each wave: 16 q-rows, one (b,h).
// Per k-tile (64): all 256 threads cooperatively stage K(b0),K(b1),VT(b0),VT(b1)
// (8KB each, XOR-swizzled col16 ^= row&7) into LDS once; both strips share.
// QK^T computed SWAPPED: mfma(K,Q) -> S^T fragment: lane(g,cc) holds
// S[q=cc][k=kb*16+g*4+r]. Benefits: bias loads are coalesced float4 per lane;
// softmax is 15 lane-local fmax + 2 shfl rounds; m/l are scalars per lane.
// P -> A-fragment via wave-private swizzled LDS (4 ds_write_b64 + 2 ds_read_b128).
// Pipeline: stage(t) -> issue bias(t+1) -> vmcnt(4) (bias stays in flight) ->
// raw s_barrier -> compute -> s_barrier.
__global__ __launch_bounds__(256, 4) void attn_kernel(
    const u16* __restrict__ qm, const u16* __restrict__ km,
    const u16* __restrict__ vtm, const float* __restrict__ bias,
    u16* __restrict__ aout) {
  __shared__ __align__(16) u16 lKV[16384];  // K(b0) K(b1) VT(b0) VT(b1), 8KB each
  __shared__ __align__(16) u16 plds[4096];  // per-wave 16x64 P tile (swizzled)
  const int tid = threadIdx.x;
  const int lane = tid & 63, wid = tid >> 6;
  const int g = lane >> 4, cc = lane & 15;
  const int b = wid >> 1, strip = wid & 1;
  const int h = blockIdx.y;
  const int q0 = blockIdx.x * 32 + strip * 16;
  const u16* kg0 = km + ((size_t)0 * 16 + h) * 2048 * 64;
  const u16* kg1 = km + ((size_t)1 * 16 + h) * 2048 * 64;
  const u16* vg0 = vtm + ((size_t)0 * 16 + h) * 64 * 2048;
  const u16* vg1 = vtm + ((size_t)1 * 16 + h) * 64 * 2048;
  const size_t bh = (size_t)b * 16 + h;
  const u16* qbase = qm + (bh * 2048 + q0) * 64;
  const float* brow = bias + ((size_t)h * 2048 + q0 + cc) * 2048;  // this lane's q-row
  u16* lK = lKV + b * 4096;
  u16* lV = lKV + 8192 + b * 4096;
  u16* plw = plds + wid * 1024;

  // Q fragments (B-operand: lane(g,cc) = Q[q=cc][d=g*8..]); q pre-scaled.
  bf16x8 qf0 = *(const bf16x8*)&qbase[(size_t)cc * 64 + g * 8];
  bf16x8 qf1 = *(const bf16x8*)&qbase[(size_t)cc * 64 + 32 + g * 8];
  f32x4 o[4] = {};
  float mrow = -3.0e38f, lrow = 0.f;

  // cooperative stage of one 64x64 bf16 tile, XOR-swizzled (both-sides):
  // LDS dest linear in thread id; global col16 = pcol ^ (row&7).
#define STAGE_TILE(gbase, rs, loff)                                            \
  _Pragma("unroll") for (int rep = 0; rep < 2; ++rep) {                        \
    int i = rep * 256 + tid;                                                   \
    int row = i >> 3, pcol = i & 7;                                            \
    int lcol = pcol ^ (row & 7);                                               \
    g2lds16((gbase) + (size_t)row * (rs) + lcol * 8, &lKV[(loff) + i * 8]);    \
  }

  float4 bA[4], bB[4];
#pragma unroll
  for (int kb = 0; kb < 4; ++kb)
    bA[kb] = *(const float4*)(brow + kb * 16 + g * 4);

#define ATTN_STEP(BC, BN, kt_)                                                 \
  {                                                                            \
    const int k0 = (kt_) * 64;                                                 \
    const int kpre = ((kt_) + 1 < 32 ? (kt_) + 1 : (kt_)) * 64;                \
    /* stage K/V tiles for both batches (16 gl_lds per thread-group) */        \
    STAGE_TILE(kg0 + (size_t)k0 * 64, 64, 0)                                   \
    STAGE_TILE(kg1 + (size_t)k0 * 64, 64, 4096)                                \
    STAGE_TILE(vg0 + k0, 2048, 8192)                                           \
    STAGE_TILE(vg1 + k0, 2048, 12288)                                          \
    __builtin_amdgcn_sched_barrier(0);                                         \
    /* issue next bias tile (stays in flight across the stage drain) */       \
    _Pragma("unroll") for (int kb = 0; kb < 4; ++kb)                           \
        BN[kb] = *(const float4*)(brow + kpre + kb * 16 + g * 4);              \
    __builtin_amdgcn_sched_barrier(0);                                         \
    asm volatile("s_waitcnt vmcnt(4)" ::: "memory");                           \
    __builtin_amdgcn_sched_barrier(0);                                         \
    __builtin_amdgcn_s_barrier();                                              \
    __builtin_amdgcn_sched_barrier(0);                                         \
    /* S^T = K Q^T : lane(g,cc) -> S[q=cc][k=kb*16+g*4+r] */                   \
    f32x4 s[4];                                                                \
    _Pragma("unroll") for (int kb = 0; kb < 4; ++kb) {                         \
      int row = kb * 16 + cc;                                                  \
      bf16x8 ka = *(const bf16x8*)&lK[row * 64 + ((0 + g) ^ (cc & 7)) * 8];    \
      bf16x8 kbf = *(const bf16x8*)&lK[row * 64 + ((4 + g) ^ (cc & 7)) * 8];   \
      f32x4 z = {};                                                            \
      z = MFMA16(ka, qf0, z);                                                  \
      z = MFMA16(kbf, qf1, z);                                                 \
      s[kb] = z;                                                               \
    }                                                                          \
    /* + bias (coalesced float4, prefetched) */                                \
    _Pragma("unroll") for (int kb = 0; kb < 4; ++kb) {                         \
      s[kb][0] = fmaf(BC[kb].x, LOG2E, s[kb][0]);                              \
      s[kb][1] = fmaf(BC[kb].y, LOG2E, s[kb][1]);                              \
      s[kb][2] = fmaf(BC[kb].z, LOG2E, s[kb][2]);                              \
      s[kb][3] = fmaf(BC[kb].w, LOG2E, s[kb][3]);                              \
    }                                                                          \
    /* online softmax: 15 lane-local fmax + 2 shfl rounds */                   \
    float rmax = s[0][0];                                                      \
    _Pragma("unroll") for (int kb = 0; kb < 4; ++kb)                           \
        _Pragma("unroll") for (int r = 0; r < 4; ++r)                          \
            rmax = fmaxf(rmax, s[kb][r]);                                      \
    rmax = fmaxf(rmax, __shfl_xor(rmax, 16, 64));                              \
    rmax = fmaxf(rmax, __shfl_xor(rmax, 32, 64));                              \
    float mnew = fmaxf(mrow, rmax);                                            \
    float sc = __builtin_amdgcn_exp2f(mrow - mnew);                            \
    mrow = mnew;                                                               \
    float psum = 0.f;                                                          \
    _Pragma("unroll") for (int kb = 0; kb < 4; ++kb)                           \
        _Pragma("unroll") for (int r = 0; r < 4; ++r) {                        \
      s[kb][r] = __builtin_amdgcn_exp2f(s[kb][r] - mrow);                      \
      psum += s[kb][r];                                                        \
    }                                                                          \
    psum += __shfl_xor(psum, 16, 64);                                          \
    psum += __shfl_xor(psum, 32, 64);                                          \
    lrow = lrow * sc + psum;                                                   \
    /* broadcast sc from q=cc layout to O layout (q=g*4+r) */                  \
    float scb[4];                                                              \
    _Pragma("unroll") for (int r = 0; r < 4; ++r)                              \
        scb[r] = __shfl(sc, (lane & 48) | (((lane >> 4) & 3) * 4 + r), 64);    \
    _Pragma("unroll") for (int td = 0; td < 4; ++td)                           \
        _Pragma("unroll") for (int r = 0; r < 4; ++r) o[td][r] *= scb[r];      \
    /* P -> wave-private swizzled LDS (chunk ^= (cc&7)<<1, 8B units) */        \
    _Pragma("unroll") for (int kb = 0; kb < 4; ++kb) {                         \
      unsigned lo = cvt_pk_bf16(s[kb][0], s[kb][1]);                           \
      unsigned hi = cvt_pk_bf16(s[kb][2], s[kb][3]);                           \
      int ch = (kb * 4 + g) ^ ((cc & 7) << 1);                                 \
      ((uint2*)plw)[cc * 16 + ch] = make_uint2(lo, hi);                        \
    }                                                                          \
    bf16x8 pf0 = *(const bf16x8*)&plw[cc * 64 + (((2 * g) ^ ((cc & 7) << 1)) * 4)]; \
    bf16x8 pf1 = *(const bf16x8*)&plw[cc * 64 + (((8 + 2 * g) ^ ((cc & 7) << 1)) * 4)]; \
    /* O += P V (V^T tile in LDS, swizzled b128 reads) */                      \
    _Pragma("unroll") for (int td = 0; td < 4; ++td) {                         \
      int row = td * 16 + cc;                                                  \
      bf16x8 va = *(const bf16x8*)&lV[row * 64 + ((0 + g) ^ (cc & 7)) * 8];    \
      bf16x8 vb = *(const bf16x8*)&lV[row * 64 + ((4 + g) ^ (cc & 7)) * 8];    \
      o[td] = MFMA16(pf0, va, o[td]);                                          \
      o[td] = MFMA16(pf1, vb, o[td]);                                          \
    }                                                                          \
    __builtin_amdgcn_sched_barrier(0);                                         \
    __builtin_amdgcn_s_barrier();                                              \
    __builtin_amdgcn_sched_barrier(0);                                         \
  }

  for (int kt = 0; kt < 32; kt += 2) {
    ATTN_STEP(bA, bB, kt)
    ATTN_STEP(bB, bA, kt + 1)
  }
#undef ATTN_STEP
#undef STAGE_TILE

  // normalize (broadcast 1/lrow to O layout) + write [B, L, 1024] bf16
  float linv = 1.0f / lrow;
  float lb[4];
#pragma unroll
  for (int r = 0; r < 4; ++r)
    lb[r] = __shfl(linv, (lane & 48) | (((lane >> 4) & 3) * 4 + r), 64);
#pragma unroll
  for (int td = 0; td < 4; ++td)
#pragma unroll
    for (int r = 0; r < 4; ++r) {
      float val = o[td][r] * lb[r];
      int qg = q0 + g * 4 + r;
      aout[((size_t)b * 2048 + qg) * 1024 + h * 64 + td * 16 + cc] = f2bf(val);
    }
}

extern "C" void kernel_launch(void* const* d_in, const int* in_sizes, int n_in,
                              void* d_out, int out_size, void* d_ws, size_t ws_size,
                              hipStream_t stream) {
  const float* x  = (const float*)d_in[0];
  const float* rb = (const float*)d_in[1];
  const float* Wq = (const float*)d_in[2];
  const float* bq = (const float*)d_in[3];
  const float* Wk = (const float*)d_in[4];
  const float* bk = (const float*)d_in[5];
  const float* Wv = (const float*)d_in[6];
  const float* bv = (const float*)d_in[7];
  const float* Wo = (const float*)d_in[8];
  const float* bo = (const float*)d_in[9];
  float* out = (float*)d_out;
  char* ws = (char*)d_ws;

  u16* xb   = (u16*)(ws);                 // 8 MB  [4096,1024] bf16 (reused as aout)
  u16* W1b  = (u16*)(ws + (8 << 20));     // 6 MB  [3072,1024] bf16 (Wq|Wk|Wv)
  u16* Wob  = (u16*)(ws + (14 << 20));    // 2 MB  [1024,1024] bf16
  u16* qb   = (u16*)(ws + (16 << 20));    // 8 MB  [B,H,L,HD]
  u16* kb2  = (u16*)(ws + (24 << 20));    // 8 MB
  u16* vb   = (u16*)(ws + (32 << 20));    // 8 MB
  u16* vtb  = (u16*)(ws + (40 << 20));    // 8 MB  [B,H,HD,L]
  u16* aout = xb;                         // alias: xb dead after QKV GEMM

  cvt_kernel<<<2048, 256, 0, stream>>>(x, xb, 524288);
  cvt_kernel<<<512, 256, 0, stream>>>(Wq, W1b, 131072);
  cvt_kernel<<<512, 256, 0, stream>>>(Wk, W1b + (1 << 20), 131072);
  cvt_kernel<<<512, 256, 0, stream>>>(Wv, W1b + (2 << 20), 131072);
  cvt_kernel<<<512, 256, 0, stream>>>(Wo, Wob, 131072);

  gemm_bt<0><<<dim3(24, 32), 256, 0, stream>>>(xb, W1b, qb, kb2, vb, bq, bk, bv,
                                               nullptr, nullptr);
  transpose_v<<<dim3(32, 32), 256, 0, stream>>>(vb, vtb);
  attn_kernel<<<dim3(64, 16), 256, 0, stream>>>(qb, kb2, vtb, rb, aout);
  gemm_bt<1><<<dim3(8, 32), 256, 0, stream>>>(aout, Wob, nullptr, nullptr, nullptr,
                                              nullptr, nullptr, nullptr, out, bo);
}